// Round 3
// baseline (1604.739 us; speedup 1.0000x reference)
//
#include <hip/hip_runtime.h>
#include <hip/hip_bf16.h>

typedef short short8 __attribute__((ext_vector_type(8)));
typedef float f32x4 __attribute__((ext_vector_type(4)));
typedef float float4g __attribute__((ext_vector_type(4)));
typedef unsigned short ushort;

#define LOG2E 1.44269504088896f

__device__ __forceinline__ ushort f2bf_fast(float f) {
  unsigned u = __builtin_bit_cast(unsigned, f);
  return (ushort)((u + 0x8000u) >> 16);
}
__device__ __forceinline__ float sigmoid_pre(float m) {
  // m = -log2e*x  ->  1/(1+2^m) = sigmoid(x)
  return __builtin_amdgcn_rcpf(1.0f + __builtin_amdgcn_exp2f(m));
}
// merge: enabled banks (BM) get row_ror:8 of src, others keep old.
template <int BM>
__device__ __forceinline__ float pkmerge(float oldv, float srcv) {
  int o = __builtin_bit_cast(int, oldv);
  int s = __builtin_bit_cast(int, srcv);
  int r = __builtin_amdgcn_update_dpp(o, s, 0x128 /*row_ror:8*/, 0xF, BM, false);
  return __builtin_bit_cast(float, r);
}

// ---------------- prep: swizzle weights to bf16 MFMA B-fragment blocks ----------------
// wfrag layout: [w(8)][l(4)][nt(2)][kc(4)][lane(64)][8 bf16]; K = [in(64)|hidden(64)]
// l=0 "input" slot K=0..63 holds Wx = Wih0 @ Wo (pred recursion folded); its bias gets
// +Wih0@bo. Separate t0 bias set: b + Wih0@x0, x0=(0.5,0.5,0).
__global__ void prep_kernel(const float* __restrict__ Wih0, const float* __restrict__ Wihr,
                            const float* __restrict__ Whh, const float* __restrict__ bih,
                            const float* __restrict__ bhh, const float* __restrict__ Wo,
                            const float* __restrict__ bo,
                            ushort* __restrict__ wfrag, ushort* __restrict__ wofrag,
                            float* __restrict__ bsum, float* __restrict__ bsum_t0) {
  int id = blockIdx.x * 256 + threadIdx.x;
  if (id < 131072) {
    int j = id & 7, lane = (id >> 3) & 63, kc = (id >> 9) & 3, nt = (id >> 11) & 1,
        l = (id >> 12) & 3, w = id >> 14;
    int c16 = lane & 15, qq = lane >> 4;
    int gate = nt * 2 + (c16 >= 8 ? 1 : 0);
    int n = gate * 64 + w * 8 + (c16 & 7);
    int k = kc * 32 + qq * 8 + j;
    float v;
    if (k < 64) {
      if (l == 0)
        v = Wih0[n * 3 + 0] * Wo[k] + Wih0[n * 3 + 1] * Wo[64 + k] +
            Wih0[n * 3 + 2] * Wo[128 + k];
      else
        v = Wihr[((l - 1) * 256 + n) * 64 + k];
    } else {
      v = Whh[(l * 256 + n) * 64 + (k - 64)];
    }
    wfrag[id] = f2bf_fast(v);
  } else if (id < 132096) {
    int id2 = id - 131072;
    int j = id2 & 7, lane = (id2 >> 3) & 63, kc = id2 >> 9;
    int c16 = lane & 15, qq = lane >> 4;
    int k = kc * 32 + qq * 8 + j;
    float v = (c16 < 3) ? Wo[c16 * 64 + k] : 0.0f;
    wofrag[id2] = f2bf_fast(v);
  } else if (id < 133120) {
    int n2 = id - 132096;
    float v = bih[n2] + bhh[n2];
    if (n2 < 256)  // layer 0: fold Wih0 @ bo
      v += Wih0[n2 * 3 + 0] * bo[0] + Wih0[n2 * 3 + 1] * bo[1] + Wih0[n2 * 3 + 2] * bo[2];
    bsum[n2] = v;
  } else if (id < 133376) {
    int n = id - 133120;  // layer 0 @ t=0: fold Wih0 @ x0
    bsum_t0[n] = bih[n] + bhh[n] + 0.5f * (Wih0[n * 3 + 0] + Wih0[n * 3 + 1]);
  }
}

// ---------------- main persistent LSTM kernel ----------------
// 8 waves, weight-stationary (all 4 layers x 32 gate-cols per wave). 64 batch rows/block.
// h: 5 rotating swizzled LDS bf16 buffers + 1 zero buffer (t=0 layer-0 input).
// Layer 0 consumes h3(t-1) via folded Wx; pred is off the critical path (store-only).
// Swizzle: physical granule(16B) = g ^ ((row>>2)&3) -> h-write 2-way banks (free),
// A-reads stay balanced.
__global__ __launch_bounds__(512, 2)
void lstm_kernel(const float* __restrict__ conds, const float* __restrict__ W1,
                 const float* __restrict__ b1, const float* __restrict__ W2,
                 const float* __restrict__ b2, const float* __restrict__ bo,
                 const int* __restrict__ seqp,
                 const ushort* __restrict__ wfrag, const ushort* __restrict__ wofrag,
                 const float* __restrict__ bsum, const float* __restrict__ bsum_t0,
                 float* __restrict__ out) {
  // 6 h-buffers (64 rows x 72 ushort = 9216 B each) = 55296 B
  __shared__ __align__(16) char smem[6 * 9216];
  float* fc = (float*)smem;                    // prologue alias over buffers 0..1
  ushort* zb = (ushort*)(smem + 5 * 9216);     // permanent zero buffer

  const int tid = threadIdx.x;
  const int w = tid >> 6;
  const int lane = tid & 63;
  const int c16 = lane & 15;
  const int q = lane >> 4;
  const int hi16 = (c16 < 8) ? 0 : 16;   // packed-half row offset
  const int colw = w * 8 + (c16 & 7);    // this lane's h-column
  const int sA = (c16 >> 2) & 3;         // read swizzle (per-lane constant)
  const int qs8 = (q ^ sA) * 8;          // swizzled A-read col offset (ushorts)
  const int wcol = (colw & 7) + 8 * (w ^ q);  // swizzled write col
  const int T = *seqp;
  const int row0 = blockIdx.x * 64;

  // zero buffer 5 (never written again)
  for (int i = tid; i < 2304; i += 512) ((unsigned*)zb)[i] = 0u;

  // ---- prologue A: h1 = relu(conds @ W1^T + b1) -> fc ----
  {
    const int r = tid >> 3;
    const int i8 = (tid & 7) * 8;
    float xr[8];
#pragma unroll
    for (int k = 0; k < 8; ++k) xr[k] = conds[(long)(row0 + r) * 8 + k];
#pragma unroll
    for (int jj = 0; jj < 8; ++jj) {
      float s = b1[i8 + jj];
#pragma unroll
      for (int k = 0; k < 8; ++k) s = fmaf(xr[k], W1[(i8 + jj) * 8 + k], s);
      fc[r * 64 + i8 + jj] = fmaxf(s, 0.0f);
    }
  }
  __syncthreads();

  // ---- prologue B1: per-lane fp32 c0 at packed rows ----
  float cinit[2][4];
  {
    const float b2v = b2[64 + colw];
#pragma unroll
    for (int pr = 0; pr < 2; ++pr)
#pragma unroll
      for (int r = 0; r < 4; ++r) cinit[pr][r] = b2v;
    const float* w2r = W2 + (64 + colw) * 64;
    const int rbase = hi16 + q * 4;
#pragma unroll 2
    for (int k4 = 0; k4 < 16; ++k4) {
      float4g wv = *(const float4g*)(w2r + k4 * 4);
#pragma unroll
      for (int pr = 0; pr < 2; ++pr)
#pragma unroll
        for (int r = 0; r < 4; ++r) {
          float4g hv = *(const float4g*)(fc + (pr * 32 + rbase + r) * 64 + k4 * 4);
          cinit[pr][r] = fmaf(hv.x, wv.x, cinit[pr][r]);
          cinit[pr][r] = fmaf(hv.y, wv.y, cinit[pr][r]);
          cinit[pr][r] = fmaf(hv.z, wv.z, cinit[pr][r]);
          cinit[pr][r] = fmaf(hv.w, wv.w, cinit[pr][r]);
        }
    }
  }
  // ---- prologue B2: h0 cols (thread-per-row) ----
  float ce0[8];
  {
    const int rb = tid >> 3;
    const int cb = (tid & 7) * 8;
#pragma unroll
    for (int jj = 0; jj < 8; ++jj) {
      float s = b2[cb + jj];
      for (int k = 0; k < 64; k += 4) {
        float4g hv = *(const float4g*)(fc + rb * 64 + k);
        float4g wv = *(const float4g*)(W2 + (cb + jj) * 64 + k);
        s = fmaf(hv.x, wv.x, s); s = fmaf(hv.y, wv.y, s);
        s = fmaf(hv.z, wv.z, s); s = fmaf(hv.w, wv.w, s);
      }
      ce0[jj] = s;
    }
  }
  __syncthreads();

  // ---- prologue C: scatter h0 into buffers 0..3 (swizzled, b128 stores) ----
  {
    const int rb = tid >> 3;
    const int gsw = ((tid & 7) ^ ((rb >> 2) & 3)) * 8;
    short8 hv;
#pragma unroll
    for (int jj = 0; jj < 8; ++jj) hv[jj] = (short)f2bf_fast(ce0[jj]);
#pragma unroll
    for (int b = 0; b < 4; ++b)
      *(short8*)((ushort*)(smem + b * 9216) + rb * 72 + gsw) = hv;
  }

  // ---- weight fragments -> registers ----
  short8 wreg[4][2][4];
  {
    const ushort* base = wfrag + w * 16384;
#pragma unroll
    for (int l = 0; l < 4; ++l)
#pragma unroll
      for (int nt = 0; nt < 2; ++nt)
#pragma unroll
        for (int kc = 0; kc < 4; ++kc)
          wreg[l][nt][kc] = *(const short8*)(base + (((l * 2 + nt) * 4 + kc) * 64 + lane) * 8);
  }
  short8 wo0 = *(const short8*)(wofrag + lane * 8);
  short8 wo1 = *(const short8*)(wofrag + 512 + lane * 8);

  // pre-scaled gate biases
  float bti[4], btf[4], btg[4], bto[4];
#pragma unroll
  for (int l = 0; l < 4; ++l) {
    bti[l] = -LOG2E * bsum[l * 256 + colw];
    btf[l] = -LOG2E * bsum[l * 256 + 64 + colw];
    btg[l] = -2.0f * LOG2E * bsum[l * 256 + 128 + colw];
    bto[l] = -LOG2E * bsum[l * 256 + 192 + colw];
  }
  const float bti_0 = -LOG2E * bsum_t0[colw];
  const float btf_0 = -LOG2E * bsum_t0[64 + colw];
  const float btg_0 = -2.0f * LOG2E * bsum_t0[128 + colw];
  const float bto_0 = -LOG2E * bsum_t0[192 + colw];
  const float boc = (c16 < 3) ? bo[c16] : 0.0f;

  // c-state fp32, packed layout
  float creg[4][2][4];
#pragma unroll
  for (int l = 0; l < 4; ++l)
#pragma unroll
    for (int pr = 0; pr < 2; ++pr)
#pragma unroll
      for (int r = 0; r < 4; ++r) creg[l][pr][r] = cinit[pr][r];

  int cur[4] = {0, 1, 2, 3};
  int spare = 4;
  __syncthreads();

  f32x4 accA[4], accB[4];
  for (int t = 0; t < T; ++t) {
    const ushort* h3p = (t == 0) ? zb : (const ushort*)(smem + cur[3] * 9216);
    const float bI0 = (t == 0) ? bti_0 : bti[0];
    const float bF0 = (t == 0) ? btf_0 : btf[0];
    const float bG0 = (t == 0) ? btg_0 : btg[0];
    const float bO0 = (t == 0) ? bto_0 : bto[0];
#pragma unroll
    for (int l = 0; l < 4; ++l) {
      __syncthreads();  // h_{l-1} (or h3 prev) visible; old readers done
      const ushort* hc = (const ushort*)(smem + cur[l] * 9216);
      const ushort* hp = (l == 0) ? h3p : (const ushort*)(smem + cur[l - 1] * 9216);
      // ---- MFMA phase (uniform 8 MFMA) ----
#pragma unroll
      for (int mt = 0; mt < 4; ++mt) {
        const int arow = mt * 16 + c16;
        short8 a0 = *(const short8*)(hp + arow * 72 + qs8);
        short8 a1v = *(const short8*)(hp + arow * 72 + 32 + qs8);
        short8 a2 = *(const short8*)(hc + arow * 72 + qs8);
        short8 a3 = *(const short8*)(hc + arow * 72 + 32 + qs8);
        f32x4 A0 = {0.f, 0.f, 0.f, 0.f}, A1 = {0.f, 0.f, 0.f, 0.f};
        A0 = __builtin_amdgcn_mfma_f32_16x16x32_bf16(a0, wreg[l][0][0], A0, 0, 0, 0);
        A1 = __builtin_amdgcn_mfma_f32_16x16x32_bf16(a0, wreg[l][1][0], A1, 0, 0, 0);
        A0 = __builtin_amdgcn_mfma_f32_16x16x32_bf16(a1v, wreg[l][0][1], A0, 0, 0, 0);
        A1 = __builtin_amdgcn_mfma_f32_16x16x32_bf16(a1v, wreg[l][1][1], A1, 0, 0, 0);
        A0 = __builtin_amdgcn_mfma_f32_16x16x32_bf16(a2, wreg[l][0][2], A0, 0, 0, 0);
        A1 = __builtin_amdgcn_mfma_f32_16x16x32_bf16(a2, wreg[l][1][2], A1, 0, 0, 0);
        A0 = __builtin_amdgcn_mfma_f32_16x16x32_bf16(a3, wreg[l][0][3], A0, 0, 0, 0);
        A1 = __builtin_amdgcn_mfma_f32_16x16x32_bf16(a3, wreg[l][1][3], A1, 0, 0, 0);
        accA[mt] = A0; accB[mt] = A1;
      }
      // ---- pred (off critical path): waves 0-3 emit out[t-1] from h3(t-1) ----
      if (l == 0 && w < 4 && t > 0) {
        const int arow = w * 16 + c16;
        short8 p0 = *(const short8*)(h3p + arow * 72 + qs8);
        short8 p1 = *(const short8*)(h3p + arow * 72 + 32 + qs8);
        f32x4 P = {0.f, 0.f, 0.f, 0.f};
        P = __builtin_amdgcn_mfma_f32_16x16x32_bf16(p0, wo0, P, 0, 0, 0);
        P = __builtin_amdgcn_mfma_f32_16x16x32_bf16(p1, wo1, P, 0, 0, 0);
        if (c16 < 3) {
#pragma unroll
          for (int r = 0; r < 4; ++r) {
            int rloc = w * 16 + q * 4 + r;
            out[(long)(row0 + rloc) * (3 * T) + (long)(t - 1) * 3 + c16] = P[r] + boc;
          }
        }
      }
      // ---- packed activation: write new h_l into spare (swizzled, 2-way banks) ----
      {
        const float bI = (l == 0) ? bI0 : bti[l];
        const float bF = (l == 0) ? bF0 : btf[l];
        const float bG = (l == 0) ? bG0 : btg[l];
        const float bO = (l == 0) ? bO0 : bto[l];
        ushort* wbuf = (ushort*)(smem + spare * 9216);
#pragma unroll
        for (int pr = 0; pr < 2; ++pr) {
          const int mtA = pr * 2, mtB = pr * 2 + 1;
          ushort* wb = wbuf + (pr * 32 + hi16 + q * 4) * 72 + wcol;
#pragma unroll
          for (int r = 0; r < 4; ++r) {
            float ipk = pkmerge<0xC>(accA[mtA][r], accA[mtB][r]);
            float fpk = pkmerge<0x3>(accA[mtB][r], accA[mtA][r]);
            float gpk = pkmerge<0xC>(accB[mtA][r], accB[mtB][r]);
            float opk = pkmerge<0x3>(accB[mtB][r], accB[mtA][r]);
            float si = sigmoid_pre(fmaf(ipk, -LOG2E, bI));
            float sf = sigmoid_pre(fmaf(fpk, -LOG2E, bF));
            float so = sigmoid_pre(fmaf(opk, -LOG2E, bO));
            float tg = fmaf(sigmoid_pre(fmaf(gpk, -2.0f * LOG2E, bG)), 2.0f, -1.0f);
            float cn = fmaf(sf, creg[l][pr][r], si * tg);
            creg[l][pr][r] = cn;
            float tc = fmaf(sigmoid_pre(cn * (2.0f * LOG2E)), -2.0f, 1.0f);
            wb[r * 72] = f2bf_fast(so * tc);
          }
        }
      }
      const int sp = spare; spare = cur[l]; cur[l] = sp;  // rotate
    }
  }
  // ---- final pred: out[T-1] from h3(T-1) ----
  __syncthreads();
  if (w < 4) {
    const ushort* h3 = (const ushort*)(smem + cur[3] * 9216);
    const int arow = w * 16 + c16;
    short8 p0 = *(const short8*)(h3 + arow * 72 + qs8);
    short8 p1 = *(const short8*)(h3 + arow * 72 + 32 + qs8);
    f32x4 P = {0.f, 0.f, 0.f, 0.f};
    P = __builtin_amdgcn_mfma_f32_16x16x32_bf16(p0, wo0, P, 0, 0, 0);
    P = __builtin_amdgcn_mfma_f32_16x16x32_bf16(p1, wo1, P, 0, 0, 0);
    if (c16 < 3) {
#pragma unroll
      for (int r = 0; r < 4; ++r) {
        int rloc = w * 16 + q * 4 + r;
        out[(long)(row0 + rloc) * (3 * T) + (long)(T - 1) * 3 + c16] = P[r] + boc;
      }
    }
  }
}

extern "C" void kernel_launch(void* const* d_in, const int* in_sizes, int n_in,
                              void* d_out, int out_size, void* d_ws, size_t ws_size,
                              hipStream_t stream) {
  const float* conds = (const float*)d_in[0];
  const float* W1    = (const float*)d_in[1];
  const float* b1    = (const float*)d_in[2];
  const float* W2    = (const float*)d_in[3];
  const float* b2    = (const float*)d_in[4];
  const float* Wih0  = (const float*)d_in[5];
  const float* Wihr  = (const float*)d_in[6];
  const float* Whh   = (const float*)d_in[7];
  const float* bih   = (const float*)d_in[8];
  const float* bhh   = (const float*)d_in[9];
  const float* Wo    = (const float*)d_in[10];
  const float* bo    = (const float*)d_in[11];
  const int*   seqp  = (const int*)d_in[12];

  const int B = in_sizes[0] / 8;  // 65536

  ushort* wfrag = (ushort*)d_ws;             // 131072 shorts
  ushort* wofrag = wfrag + 131072;           // 1024 shorts
  float* bsum = (float*)(wofrag + 1024);     // 1024 floats
  float* bsum_t0 = bsum + 1024;              // 256 floats

  prep_kernel<<<521, 256, 0, stream>>>(Wih0, Wihr, Whh, bih, bhh, Wo, bo,
                                       wfrag, wofrag, bsum, bsum_t0);
  lstm_kernel<<<B / 64, 512, 0, stream>>>(conds, W1, b1, W2, b2, bo, seqp,
                                          wfrag, wofrag, bsum, bsum_t0, (float*)d_out);
}

// Round 4
// 1520.572 us; speedup vs baseline: 1.0554x; 1.0554x over previous
//
#include <hip/hip_runtime.h>
#include <hip/hip_bf16.h>

typedef short short8 __attribute__((ext_vector_type(8)));
typedef float f32x4 __attribute__((ext_vector_type(4)));
typedef float float4g __attribute__((ext_vector_type(4)));
typedef unsigned short ushort;

#define LOG2E 1.44269504088896f

__device__ __forceinline__ ushort f2bf_fast(float f) {
  unsigned u = __builtin_bit_cast(unsigned, f);
  return (ushort)((u + 0x8000u) >> 16);
}
// merge: enabled banks (BM) get row_ror:8 of src, others keep old.
template <int BM>
__device__ __forceinline__ float pkmerge(float oldv, float srcv) {
  int o = __builtin_bit_cast(int, oldv);
  int s = __builtin_bit_cast(int, srcv);
  int r = __builtin_amdgcn_update_dpp(o, s, 0x128 /*row_ror:8*/, 0xF, BM, false);
  return __builtin_bit_cast(float, r);
}

// ---------------- prep: swizzle weights to bf16 MFMA B-fragment blocks ----------------
// wfrag layout: [w(8)][l(4)][nt(2)][kc(4)][lane(64)][8 bf16]; K = [in(64)|hidden(64)]
// l=0 "input" slot K=0..63 holds Wx = Wih0 @ Wo (pred recursion folded); its bias gets
// +Wih0@bo. Separate t0 bias set: b + Wih0@x0, x0=(0.5,0.5,0).
__global__ void prep_kernel(const float* __restrict__ Wih0, const float* __restrict__ Wihr,
                            const float* __restrict__ Whh, const float* __restrict__ bih,
                            const float* __restrict__ bhh, const float* __restrict__ Wo,
                            const float* __restrict__ bo,
                            ushort* __restrict__ wfrag, ushort* __restrict__ wofrag,
                            float* __restrict__ bsum, float* __restrict__ bsum_t0) {
  int id = blockIdx.x * 256 + threadIdx.x;
  if (id < 131072) {
    int j = id & 7, lane = (id >> 3) & 63, kc = (id >> 9) & 3, nt = (id >> 11) & 1,
        l = (id >> 12) & 3, w = id >> 14;
    int c16 = lane & 15, qq = lane >> 4;
    int gate = nt * 2 + (c16 >= 8 ? 1 : 0);
    int n = gate * 64 + w * 8 + (c16 & 7);
    int k = kc * 32 + qq * 8 + j;
    float v;
    if (k < 64) {
      if (l == 0)
        v = Wih0[n * 3 + 0] * Wo[k] + Wih0[n * 3 + 1] * Wo[64 + k] +
            Wih0[n * 3 + 2] * Wo[128 + k];
      else
        v = Wihr[((l - 1) * 256 + n) * 64 + k];
    } else {
      v = Whh[(l * 256 + n) * 64 + (k - 64)];
    }
    wfrag[id] = f2bf_fast(v);
  } else if (id < 132096) {
    int id2 = id - 131072;
    int j = id2 & 7, lane = (id2 >> 3) & 63, kc = id2 >> 9;
    int c16 = lane & 15, qq = lane >> 4;
    int k = kc * 32 + qq * 8 + j;
    float v = (c16 < 3) ? Wo[c16 * 64 + k] : 0.0f;
    wofrag[id2] = f2bf_fast(v);
  } else if (id < 133120) {
    int n2 = id - 132096;
    float v = bih[n2] + bhh[n2];
    if (n2 < 256)  // layer 0: fold Wih0 @ bo
      v += Wih0[n2 * 3 + 0] * bo[0] + Wih0[n2 * 3 + 1] * bo[1] + Wih0[n2 * 3 + 2] * bo[2];
    bsum[n2] = v;
  } else if (id < 133376) {
    int n = id - 133120;  // layer 0 @ t=0: fold Wih0 @ x0
    bsum_t0[n] = bih[n] + bhh[n] + 0.5f * (Wih0[n * 3 + 0] + Wih0[n * 3 + 1]);
  }
}

// ---------------- main persistent LSTM kernel ----------------
// 8 waves, weight-stationary (all 4 layers x 32 gate-cols per wave). 64 batch rows/block.
// h: 5 rotating swizzled LDS bf16 buffers + 1 zero buffer (t=0 layer-0 input).
// Layer 0 consumes h3(t-1) via folded Wx; pred is off the critical path (store-only).
// Pipelining: recurrent-half MFMAs issued PRE-barrier (hc stable since t-1); input-half
// MFMAs interleaved with activation per mt-pair; MFMAs stay in flight across s_barrier.
// Activation: shared-denominator form -> 5 exp2 + 2 rcp per element (was 5+5).
__global__ __launch_bounds__(512, 2)
void lstm_kernel(const float* __restrict__ conds, const float* __restrict__ W1,
                 const float* __restrict__ b1, const float* __restrict__ W2,
                 const float* __restrict__ b2, const float* __restrict__ bo,
                 const int* __restrict__ seqp,
                 const ushort* __restrict__ wfrag, const ushort* __restrict__ wofrag,
                 const float* __restrict__ bsum, const float* __restrict__ bsum_t0,
                 float* __restrict__ out) {
  // 6 h-buffers (64 rows x 72 ushort = 9216 B each) = 55296 B
  __shared__ __align__(16) char smem[6 * 9216];
  float* fc = (float*)smem;                    // prologue alias over buffers 0..1
  ushort* zb = (ushort*)(smem + 5 * 9216);     // permanent zero buffer

  const int tid = threadIdx.x;
  const int w = tid >> 6;
  const int lane = tid & 63;
  const int c16 = lane & 15;
  const int q = lane >> 4;
  const int hi16 = (c16 < 8) ? 0 : 16;   // packed-half row offset
  const int colw = w * 8 + (c16 & 7);    // this lane's h-column
  const int sA = (c16 >> 2) & 3;         // read swizzle (per-lane constant)
  const int qs8 = (q ^ sA) * 8;          // swizzled A-read col offset (ushorts)
  const int wcol = (colw & 7) + 8 * (w ^ q);  // swizzled write col
  const int T = *seqp;
  const int row0 = blockIdx.x * 64;

  // zero buffer 5 (never written again)
  for (int i = tid; i < 2304; i += 512) ((unsigned*)zb)[i] = 0u;

  // ---- prologue A: h1 = relu(conds @ W1^T + b1) -> fc ----
  {
    const int r = tid >> 3;
    const int i8 = (tid & 7) * 8;
    float xr[8];
#pragma unroll
    for (int k = 0; k < 8; ++k) xr[k] = conds[(long)(row0 + r) * 8 + k];
#pragma unroll
    for (int jj = 0; jj < 8; ++jj) {
      float s = b1[i8 + jj];
#pragma unroll
      for (int k = 0; k < 8; ++k) s = fmaf(xr[k], W1[(i8 + jj) * 8 + k], s);
      fc[r * 64 + i8 + jj] = fmaxf(s, 0.0f);
    }
  }
  __syncthreads();

  // ---- prologue B1: per-lane fp32 c0 at packed rows ----
  float cinit[2][4];
  {
    const float b2v = b2[64 + colw];
#pragma unroll
    for (int pr = 0; pr < 2; ++pr)
#pragma unroll
      for (int r = 0; r < 4; ++r) cinit[pr][r] = b2v;
    const float* w2r = W2 + (64 + colw) * 64;
    const int rbase = hi16 + q * 4;
#pragma unroll 2
    for (int k4 = 0; k4 < 16; ++k4) {
      float4g wv = *(const float4g*)(w2r + k4 * 4);
#pragma unroll
      for (int pr = 0; pr < 2; ++pr)
#pragma unroll
        for (int r = 0; r < 4; ++r) {
          float4g hv = *(const float4g*)(fc + (pr * 32 + rbase + r) * 64 + k4 * 4);
          cinit[pr][r] = fmaf(hv.x, wv.x, cinit[pr][r]);
          cinit[pr][r] = fmaf(hv.y, wv.y, cinit[pr][r]);
          cinit[pr][r] = fmaf(hv.z, wv.z, cinit[pr][r]);
          cinit[pr][r] = fmaf(hv.w, wv.w, cinit[pr][r]);
        }
    }
  }
  // ---- prologue B2: h0 cols (thread-per-row) ----
  float ce0[8];
  {
    const int rb = tid >> 3;
    const int cb = (tid & 7) * 8;
#pragma unroll
    for (int jj = 0; jj < 8; ++jj) {
      float s = b2[cb + jj];
      for (int k = 0; k < 64; k += 4) {
        float4g hv = *(const float4g*)(fc + rb * 64 + k);
        float4g wv = *(const float4g*)(W2 + (cb + jj) * 64 + k);
        s = fmaf(hv.x, wv.x, s); s = fmaf(hv.y, wv.y, s);
        s = fmaf(hv.z, wv.z, s); s = fmaf(hv.w, wv.w, s);
      }
      ce0[jj] = s;
    }
  }
  __syncthreads();

  // ---- prologue C: scatter h0 into buffers 0..3 (swizzled, b128 stores) ----
  {
    const int rb = tid >> 3;
    const int gsw = ((tid & 7) ^ ((rb >> 2) & 3)) * 8;
    short8 hv;
#pragma unroll
    for (int jj = 0; jj < 8; ++jj) hv[jj] = (short)f2bf_fast(ce0[jj]);
#pragma unroll
    for (int b = 0; b < 4; ++b)
      *(short8*)((ushort*)(smem + b * 9216) + rb * 72 + gsw) = hv;
  }

  // ---- weight fragments -> registers ----
  short8 wreg[4][2][4];
  {
    const ushort* base = wfrag + w * 16384;
#pragma unroll
    for (int l = 0; l < 4; ++l)
#pragma unroll
      for (int nt = 0; nt < 2; ++nt)
#pragma unroll
        for (int kc = 0; kc < 4; ++kc)
          wreg[l][nt][kc] = *(const short8*)(base + (((l * 2 + nt) * 4 + kc) * 64 + lane) * 8);
  }
  short8 wo0 = *(const short8*)(wofrag + lane * 8);
  short8 wo1 = *(const short8*)(wofrag + 512 + lane * 8);

  // pre-scaled gate biases
  float bti[4], btf[4], btg[4], bto[4];
#pragma unroll
  for (int l = 0; l < 4; ++l) {
    bti[l] = -LOG2E * bsum[l * 256 + colw];
    btf[l] = -LOG2E * bsum[l * 256 + 64 + colw];
    btg[l] = -2.0f * LOG2E * bsum[l * 256 + 128 + colw];
    bto[l] = -LOG2E * bsum[l * 256 + 192 + colw];
  }
  const float bti_0 = -LOG2E * bsum_t0[colw];
  const float btf_0 = -LOG2E * bsum_t0[64 + colw];
  const float btg_0 = -2.0f * LOG2E * bsum_t0[128 + colw];
  const float bto_0 = -LOG2E * bsum_t0[192 + colw];
  const float boc = (c16 < 3) ? bo[c16] : 0.0f;

  // c-state fp32, packed layout
  float creg[4][2][4];
#pragma unroll
  for (int l = 0; l < 4; ++l)
#pragma unroll
    for (int pr = 0; pr < 2; ++pr)
#pragma unroll
      for (int r = 0; r < 4; ++r) creg[l][pr][r] = cinit[pr][r];

  int cur[4] = {0, 1, 2, 3};
  int spare = 4;
  __syncthreads();

  f32x4 accA[4], accB[4];
  for (int t = 0; t < T; ++t) {
    const ushort* h3p = (t == 0) ? zb : (const ushort*)(smem + cur[3] * 9216);
#pragma unroll
    for (int l = 0; l < 4; ++l) {
      const ushort* hc = (const ushort*)(smem + cur[l] * 9216);
      // ---- PRE-barrier: recurrent-half MFMAs (hc = h_l(t-1), stable) ----
#pragma unroll
      for (int mt = 0; mt < 4; ++mt) {
        const int arow = mt * 16 + c16;
        short8 a2 = *(const short8*)(hc + arow * 72 + qs8);
        short8 a3 = *(const short8*)(hc + arow * 72 + 32 + qs8);
        f32x4 A0 = {0.f, 0.f, 0.f, 0.f}, A1 = {0.f, 0.f, 0.f, 0.f};
        A0 = __builtin_amdgcn_mfma_f32_16x16x32_bf16(a2, wreg[l][0][2], A0, 0, 0, 0);
        A1 = __builtin_amdgcn_mfma_f32_16x16x32_bf16(a2, wreg[l][1][2], A1, 0, 0, 0);
        A0 = __builtin_amdgcn_mfma_f32_16x16x32_bf16(a3, wreg[l][0][3], A0, 0, 0, 0);
        A1 = __builtin_amdgcn_mfma_f32_16x16x32_bf16(a3, wreg[l][1][3], A1, 0, 0, 0);
        accA[mt] = A0; accB[mt] = A1;
      }
      __syncthreads();  // h_{l-1}(t) visible; old-spare readers done
      const ushort* hp = (l == 0) ? h3p : (const ushort*)(smem + cur[l - 1] * 9216);
      ushort* wbuf = (ushort*)(smem + spare * 9216);
      const float bI = (l == 0) ? ((t == 0) ? bti_0 : bti[0]) : bti[l];
      const float bF = (l == 0) ? ((t == 0) ? btf_0 : btf[0]) : btf[l];
      const float bG = (l == 0) ? ((t == 0) ? btg_0 : btg[0]) : btg[l];
      const float bO = (l == 0) ? ((t == 0) ? bto_0 : bto[0]) : bto[l];
      // ---- POST-barrier: input-half MFMAs + activation, per mt-pair ----
#pragma unroll
      for (int pr = 0; pr < 2; ++pr) {
        const int mtA = pr * 2, mtB = pr * 2 + 1;
#pragma unroll
        for (int mm = 0; mm < 2; ++mm) {
          const int mt = pr * 2 + mm;
          const int arow = mt * 16 + c16;
          short8 a0 = *(const short8*)(hp + arow * 72 + qs8);
          short8 a1v = *(const short8*)(hp + arow * 72 + 32 + qs8);
          accA[mt] = __builtin_amdgcn_mfma_f32_16x16x32_bf16(a0, wreg[l][0][0], accA[mt], 0, 0, 0);
          accB[mt] = __builtin_amdgcn_mfma_f32_16x16x32_bf16(a0, wreg[l][1][0], accB[mt], 0, 0, 0);
          accA[mt] = __builtin_amdgcn_mfma_f32_16x16x32_bf16(a1v, wreg[l][0][1], accA[mt], 0, 0, 0);
          accB[mt] = __builtin_amdgcn_mfma_f32_16x16x32_bf16(a1v, wreg[l][1][1], accB[mt], 0, 0, 0);
        }
        // shared-denominator activation (5 exp2 + 2 rcp per element)
        ushort* wb = wbuf + (pr * 32 + hi16 + q * 4) * 72 + wcol;
#pragma unroll
        for (int r = 0; r < 4; ++r) {
          float ipk = pkmerge<0xC>(accA[mtA][r], accA[mtB][r]);
          float fpk = pkmerge<0x3>(accA[mtB][r], accA[mtA][r]);
          float gpk = pkmerge<0xC>(accB[mtA][r], accB[mtB][r]);
          float opk = pkmerge<0x3>(accB[mtB][r], accB[mtA][r]);
          float Ei = __builtin_amdgcn_exp2f(fmaf(ipk, -LOG2E, bI));
          float Ef = __builtin_amdgcn_exp2f(fmaf(fpk, -LOG2E, bF));
          float Eg = __builtin_amdgcn_exp2f(fmaf(gpk, -2.0f * LOG2E, bG));
          float Eo = __builtin_amdgcn_exp2f(fmaf(opk, -LOG2E, bO));
          float Di = 1.0f + Ei, Df = 1.0f + Ef, Dg = 1.0f + Eg, Do = 1.0f + Eo;
          float P = Di * Dg;
          float t3 = fmaf(-Eg, Df, Df);               // Df*(1-Eg)
          float num = fmaf(creg[l][pr][r], P, t3);    // c*Di*Dg + Df*(1-Eg)
          float R = __builtin_amdgcn_rcpf(Df * P);
          float cn = num * R;
          creg[l][pr][r] = cn;
          float Ec = __builtin_amdgcn_exp2f(cn * (-2.0f * LOG2E));
          float Dc = 1.0f + Ec;
          float R2 = __builtin_amdgcn_rcpf(Do * Dc);
          float h = (1.0f - Ec) * R2;                 // sig(o)*tanh(cn)
          wb[r * 72] = f2bf_fast(h);
        }
      }
      // ---- pred (off critical path): waves 0-3 emit out[t-1] from h3(t-1) ----
      if (l == 0 && w < 4 && t > 0) {
        const int arow = w * 16 + c16;
        short8 p0 = *(const short8*)(h3p + arow * 72 + qs8);
        short8 p1 = *(const short8*)(h3p + arow * 72 + 32 + qs8);
        f32x4 P = {0.f, 0.f, 0.f, 0.f};
        P = __builtin_amdgcn_mfma_f32_16x16x32_bf16(p0, wo0, P, 0, 0, 0);
        P = __builtin_amdgcn_mfma_f32_16x16x32_bf16(p1, wo1, P, 0, 0, 0);
        if (c16 < 3) {
#pragma unroll
          for (int r = 0; r < 4; ++r) {
            int rloc = w * 16 + q * 4 + r;
            out[(long)(row0 + rloc) * (3 * T) + (long)(t - 1) * 3 + c16] = P[r] + boc;
          }
        }
      }
      const int sp = spare; spare = cur[l]; cur[l] = sp;  // rotate
    }
  }
  // ---- final pred: out[T-1] from h3(T-1) ----
  __syncthreads();
  if (w < 4) {
    const ushort* h3 = (const ushort*)(smem + cur[3] * 9216);
    const int arow = w * 16 + c16;
    short8 p0 = *(const short8*)(h3 + arow * 72 + qs8);
    short8 p1 = *(const short8*)(h3 + arow * 72 + 32 + qs8);
    f32x4 P = {0.f, 0.f, 0.f, 0.f};
    P = __builtin_amdgcn_mfma_f32_16x16x32_bf16(p0, wo0, P, 0, 0, 0);
    P = __builtin_amdgcn_mfma_f32_16x16x32_bf16(p1, wo1, P, 0, 0, 0);
    if (c16 < 3) {
#pragma unroll
      for (int r = 0; r < 4; ++r) {
        int rloc = w * 16 + q * 4 + r;
        out[(long)(row0 + rloc) * (3 * T) + (long)(T - 1) * 3 + c16] = P[r] + boc;
      }
    }
  }
}

extern "C" void kernel_launch(void* const* d_in, const int* in_sizes, int n_in,
                              void* d_out, int out_size, void* d_ws, size_t ws_size,
                              hipStream_t stream) {
  const float* conds = (const float*)d_in[0];
  const float* W1    = (const float*)d_in[1];
  const float* b1    = (const float*)d_in[2];
  const float* W2    = (const float*)d_in[3];
  const float* b2    = (const float*)d_in[4];
  const float* Wih0  = (const float*)d_in[5];
  const float* Wihr  = (const float*)d_in[6];
  const float* Whh   = (const float*)d_in[7];
  const float* bih   = (const float*)d_in[8];
  const float* bhh   = (const float*)d_in[9];
  const float* Wo    = (const float*)d_in[10];
  const float* bo    = (const float*)d_in[11];
  const int*   seqp  = (const int*)d_in[12];

  const int B = in_sizes[0] / 8;  // 65536

  ushort* wfrag = (ushort*)d_ws;             // 131072 shorts
  ushort* wofrag = wfrag + 131072;           // 1024 shorts
  float* bsum = (float*)(wofrag + 1024);     // 1024 floats
  float* bsum_t0 = bsum + 1024;              // 256 floats

  prep_kernel<<<521, 256, 0, stream>>>(Wih0, Wihr, Whh, bih, bhh, Wo, bo,
                                       wfrag, wofrag, bsum, bsum_t0);
  lstm_kernel<<<B / 64, 512, 0, stream>>>(conds, W1, b1, W2, b2, bo, seqp,
                                          wfrag, wofrag, bsum, bsum_t0, (float*)d_out);
}